// Round 2
// baseline (647.686 us; speedup 1.0000x reference)
//
#include <hip/hip_runtime.h>

#define N_NODES   100000
#define N_EDGES   3200000
#define N_FEAT    128
#define HIDDEN    16
#define MLP_H     100
#define N_CLASSES 12
#define N_GRAPHS  512
#define NBLK      391   // ceil(N_NODES/256)

// ---------------- degree count (in-degree via dst, no self loop) -----------
__global__ __launch_bounds__(256) void kDeg(const int* __restrict__ dst,
                                            int* __restrict__ deg) {
    int e = blockIdx.x * 256 + threadIdx.x;
    if (e < N_EDGES) atomicAdd(&deg[dst[e]], 1);
}

__global__ __launch_bounds__(256) void kDinv(const int* __restrict__ deg,
                                             float* __restrict__ dinv) {
    int i = blockIdx.x * 256 + threadIdx.x;
    if (i < N_NODES) dinv[i] = rsqrtf((float)deg[i] + 1.0f);  // +1 = self loop
}

// ---------------- hierarchical exclusive scan of deg -> off, cursor --------
__global__ __launch_bounds__(256) void kScan1(const int* __restrict__ deg,
                                              int* __restrict__ bs) {
    __shared__ int sm[256];
    int i = blockIdx.x * 256 + threadIdx.x;
    sm[threadIdx.x] = (i < N_NODES) ? deg[i] : 0;
    __syncthreads();
    for (int d = 128; d > 0; d >>= 1) {
        if (threadIdx.x < d) sm[threadIdx.x] += sm[threadIdx.x + d];
        __syncthreads();
    }
    if (threadIdx.x == 0) bs[blockIdx.x] = sm[0];
}

__global__ __launch_bounds__(512) void kScan2(int* __restrict__ bs) {
    __shared__ int sm[512];
    int t = threadIdx.x;
    int v = (t < NBLK) ? bs[t] : 0;
    sm[t] = v;
    __syncthreads();
    for (int d = 1; d < 512; d <<= 1) {
        int add = (t >= d) ? sm[t - d] : 0;
        __syncthreads();
        sm[t] += add;
        __syncthreads();
    }
    if (t < NBLK) bs[t] = sm[t] - v;  // exclusive prefix of block sums
}

__global__ __launch_bounds__(256) void kScan3(const int* __restrict__ deg,
                                              const int* __restrict__ bs,
                                              int* __restrict__ off,
                                              int* __restrict__ cursor) {
    __shared__ int sm[256];
    int t = threadIdx.x;
    int i = blockIdx.x * 256 + t;
    int d = (i < N_NODES) ? deg[i] : 0;
    sm[t] = d;
    __syncthreads();
    for (int s = 1; s < 256; s <<= 1) {
        int add = (t >= s) ? sm[t - s] : 0;
        __syncthreads();
        sm[t] += add;
        __syncthreads();
    }
    if (i < N_NODES) {
        int o = bs[blockIdx.x] + sm[t] - d;  // exclusive
        off[i] = o;
        cursor[i] = o;
    }
    if (i == 0) off[N_NODES] = N_EDGES;
}

// ---------------- CSR fill: csr[pos(dst)] = src ----------------------------
__global__ __launch_bounds__(256) void kFill(const int* __restrict__ src,
                                             const int* __restrict__ dst,
                                             int* __restrict__ cursor,
                                             int* __restrict__ csr) {
    int e = blockIdx.x * 256 + threadIdx.x;
    if (e < N_EDGES) {
        int pos = atomicAdd(&cursor[dst[e]], 1);
        csr[pos] = src[e];
    }
}

// ---------------- hp = (x @ W1) * dinv[n]  ---------------------------------
__global__ __launch_bounds__(256) void kGemm1(const float* __restrict__ x,
                                              const float* __restrict__ W1,
                                              const float* __restrict__ dinv,
                                              float* __restrict__ hp) {
    __shared__ float Ws[N_FEAT * HIDDEN];  // 8 KB
    for (int t = threadIdx.x; t < N_FEAT * HIDDEN; t += 256) Ws[t] = W1[t];
    __syncthreads();
    int n = blockIdx.x * 256 + threadIdx.x;
    if (n >= N_NODES) return;

    float acc[HIDDEN];
#pragma unroll
    for (int j = 0; j < HIDDEN; ++j) acc[j] = 0.f;

    const float4* xr = (const float4*)(x + (size_t)n * N_FEAT);
#pragma unroll 4
    for (int k4 = 0; k4 < N_FEAT / 4; ++k4) {
        float4 v = xr[k4];
        float xk[4] = {v.x, v.y, v.z, v.w};
#pragma unroll
        for (int kk = 0; kk < 4; ++kk) {
            const float4* wrow = (const float4*)&Ws[(k4 * 4 + kk) * HIDDEN];
#pragma unroll
            for (int j4 = 0; j4 < 4; ++j4) {
                float4 wv = wrow[j4];
                acc[j4 * 4 + 0] += xk[kk] * wv.x;
                acc[j4 * 4 + 1] += xk[kk] * wv.y;
                acc[j4 * 4 + 2] += xk[kk] * wv.z;
                acc[j4 * 4 + 3] += xk[kk] * wv.w;
            }
        }
    }
    float dv = dinv[n];
    float4* hr = (float4*)(hp + (size_t)n * HIDDEN);
#pragma unroll
    for (int j4 = 0; j4 < 4; ++j4)
        hr[j4] = make_float4(acc[j4 * 4 + 0] * dv, acc[j4 * 4 + 1] * dv,
                             acc[j4 * 4 + 2] * dv, acc[j4 * 4 + 3] * dv);
}

// ------- agg[n] = dinv[n] * (hp[n] + sum_{s in N(n)} hp[s]) ----------------
// 16 lanes per node (lane j = feature j); shfl-broadcast 16 edge ids at a
// time so 16 independent row loads are in flight.
__global__ __launch_bounds__(256) void kAgg(const float* __restrict__ hp,
                                            const float* __restrict__ dinv,
                                            const int* __restrict__ off,
                                            const int* __restrict__ csr,
                                            float* __restrict__ agg) {
    int gid = blockIdx.x * 256 + threadIdx.x;
    int n = gid >> 4;
    int j = gid & 15;
    if (n >= N_NODES) return;
    int beg = off[n], end = off[n + 1];
    float acc = hp[(size_t)n * HIDDEN + j];  // self loop
    for (int eb = beg; eb < end; eb += 16) {
        int mye = eb + j;
        int sid = (mye < end) ? csr[mye] : -1;
#pragma unroll
        for (int k = 0; k < 16; ++k) {
            int s = __shfl(sid, k, 16);
            if (s >= 0) acc += hp[(size_t)s * HIDDEN + j];
        }
    }
    agg[(size_t)n * HIDDEN + j] = acc * dinv[n];
}

// ------- t = relu(agg1+b1); hp2 = (t @ W2) * dinv --------------------------
__global__ __launch_bounds__(256) void kLayer2(const float* __restrict__ agg1,
                                               const float* __restrict__ W2,
                                               const float* __restrict__ b1,
                                               const float* __restrict__ dinv,
                                               float* __restrict__ hp2) {
    __shared__ float Ws[HIDDEN * HIDDEN];
    __shared__ float bs[HIDDEN];
    if (threadIdx.x < HIDDEN * HIDDEN) Ws[threadIdx.x] = W2[threadIdx.x];
    if (threadIdx.x < HIDDEN) bs[threadIdx.x] = b1[threadIdx.x];
    __syncthreads();
    int n = blockIdx.x * 256 + threadIdx.x;
    if (n >= N_NODES) return;

    float t[HIDDEN];
    const float4* a1r = (const float4*)(agg1 + (size_t)n * HIDDEN);
#pragma unroll
    for (int j4 = 0; j4 < 4; ++j4) {
        float4 av = a1r[j4];
        t[j4 * 4 + 0] = fmaxf(av.x + bs[j4 * 4 + 0], 0.f);
        t[j4 * 4 + 1] = fmaxf(av.y + bs[j4 * 4 + 1], 0.f);
        t[j4 * 4 + 2] = fmaxf(av.z + bs[j4 * 4 + 2], 0.f);
        t[j4 * 4 + 3] = fmaxf(av.w + bs[j4 * 4 + 3], 0.f);
    }
    float acc[HIDDEN];
#pragma unroll
    for (int j = 0; j < HIDDEN; ++j) acc[j] = 0.f;
#pragma unroll
    for (int k = 0; k < HIDDEN; ++k) {
        const float4* wrow = (const float4*)&Ws[k * HIDDEN];
#pragma unroll
        for (int j4 = 0; j4 < 4; ++j4) {
            float4 wv = wrow[j4];
            acc[j4 * 4 + 0] += t[k] * wv.x;
            acc[j4 * 4 + 1] += t[k] * wv.y;
            acc[j4 * 4 + 2] += t[k] * wv.z;
            acc[j4 * 4 + 3] += t[k] * wv.w;
        }
    }
    float dv = dinv[n];
    float4* hr = (float4*)(hp2 + (size_t)n * HIDDEN);
#pragma unroll
    for (int j4 = 0; j4 < 4; ++j4)
        hr[j4] = make_float4(acc[j4 * 4 + 0] * dv, acc[j4 * 4 + 1] * dv,
                             acc[j4 * 4 + 2] * dv, acc[j4 * 4 + 3] * dv);
}

// ------- v = relu(agg2+b2); pooled[batch[n]] += v --------------------------
__global__ __launch_bounds__(256) void kPool(const float* __restrict__ agg2,
                                             const float* __restrict__ b2,
                                             const int* __restrict__ batch,
                                             float* __restrict__ pooled) {
    int gid = blockIdx.x * 256 + threadIdx.x;
    int n = gid >> 4;
    int j = gid & 15;
    if (n >= N_NODES) return;
    float v = fmaxf(agg2[(size_t)n * HIDDEN + j] + b2[j], 0.f);
    unsafeAtomicAdd(&pooled[(size_t)batch[n] * HIDDEN + j], v);
}

// ------- g=relu(pooled); g1=relu(g@lw1+lb1); out=g1@lw2+lb2 ----------------
__global__ __launch_bounds__(64) void kMlp(const float* __restrict__ pooled,
                                           const float* __restrict__ lw1,
                                           const float* __restrict__ lb1,
                                           const float* __restrict__ lw2,
                                           const float* __restrict__ lb2,
                                           float* __restrict__ out) {
    int g = blockIdx.x * 64 + threadIdx.x;
    if (g >= N_GRAPHS) return;
    float gv[HIDDEN];
#pragma unroll
    for (int k = 0; k < HIDDEN; ++k)
        gv[k] = fmaxf(pooled[(size_t)g * HIDDEN + k], 0.f);
    float o[N_CLASSES];
#pragma unroll
    for (int c = 0; c < N_CLASSES; ++c) o[c] = lb2[c];
    for (int j = 0; j < MLP_H; ++j) {
        float s = lb1[j];
#pragma unroll
        for (int k = 0; k < HIDDEN; ++k) s += gv[k] * lw1[k * MLP_H + j];
        s = fmaxf(s, 0.f);
#pragma unroll
        for (int c = 0; c < N_CLASSES; ++c) o[c] += s * lw2[j * N_CLASSES + c];
    }
#pragma unroll
    for (int c = 0; c < N_CLASSES; ++c) out[(size_t)g * N_CLASSES + c] = o[c];
}

extern "C" void kernel_launch(void* const* d_in, const int* in_sizes, int n_in,
                              void* d_out, int out_size, void* d_ws,
                              size_t ws_size, hipStream_t stream) {
    const float* x     = (const float*)d_in[0];
    const int*   ei    = (const int*)d_in[1];
    const int*   batch = (const int*)d_in[2];
    const float* W1    = (const float*)d_in[3];
    const float* b1    = (const float*)d_in[4];
    const float* W2    = (const float*)d_in[5];
    const float* b2    = (const float*)d_in[6];
    const float* lw1   = (const float*)d_in[7];
    const float* lb1   = (const float*)d_in[8];
    const float* lw2   = (const float*)d_in[9];
    const float* lb2   = (const float*)d_in[10];
    float* out = (float*)d_out;

    const int* src = ei;
    const int* dst = ei + N_EDGES;

    // workspace layout (bytes)
    char* ws = (char*)d_ws;
    int*   deg    = (int*)(ws + 0);          //   400000
    float* dinv   = (float*)(ws + 401408);   //   400000
    int*   off    = (int*)(ws + 802816);     //   400004 (N+1)
    int*   cursor = (int*)(ws + 1204224);    //   400000
    int*   bsums  = (int*)(ws + 1605632);    //     1564
    float* hp     = (float*)(ws + 1608704);  //  6400000 (h1', then h2')
    float* agg    = (float*)(ws + 8009728);  //  6400000 (agg1, then agg2)
    int*   csr    = (int*)(ws + 14410752);   // 12800000
    float* pooled = (float*)(ws + 27211776); //    32768

    hipMemsetAsync(deg, 0, 400000, stream);
    hipMemsetAsync(pooled, 0, 32768, stream);

    kDeg<<<(N_EDGES + 255) / 256, 256, 0, stream>>>(dst, deg);
    kDinv<<<NBLK, 256, 0, stream>>>(deg, dinv);
    kScan1<<<NBLK, 256, 0, stream>>>(deg, bsums);
    kScan2<<<1, 512, 0, stream>>>(bsums);
    kScan3<<<NBLK, 256, 0, stream>>>(deg, bsums, off, cursor);
    kFill<<<(N_EDGES + 255) / 256, 256, 0, stream>>>(src, dst, cursor, csr);

    kGemm1<<<NBLK, 256, 0, stream>>>(x, W1, dinv, hp);
    kAgg<<<(N_NODES * HIDDEN + 255) / 256, 256, 0, stream>>>(hp, dinv, off, csr, agg);
    kLayer2<<<NBLK, 256, 0, stream>>>(agg, W2, b1, dinv, hp);
    kAgg<<<(N_NODES * HIDDEN + 255) / 256, 256, 0, stream>>>(hp, dinv, off, csr, agg);
    kPool<<<(N_NODES * HIDDEN + 255) / 256, 256, 0, stream>>>(agg, b2, batch, pooled);
    kMlp<<<(N_GRAPHS + 63) / 64, 64, 0, stream>>>(pooled, lw1, lb1, lw2, lb2, out);
}

// Round 3
// 607.797 us; speedup vs baseline: 1.0656x; 1.0656x over previous
//
#include <hip/hip_runtime.h>

#define N_NODES   100000
#define N_EDGES   3200000
#define N_FEAT    128
#define HIDDEN    16
#define MLP_H     100
#define N_CLASSES 12
#define N_GRAPHS  512
#define NBLK      391            // ceil(N_NODES/256)
#define NBUCK     782            // ceil(N_NODES/128), 128 nodes per bucket
#define CPAD      16             // counter padding (ints) -> 1 counter / 64B

// ---- bucket histogram: bcnt[d>>7]++ ---------------------------------------
__global__ __launch_bounds__(256) void kBCnt(const int* __restrict__ dst,
                                             int* __restrict__ bcnt) {
    int e = blockIdx.x * 256 + threadIdx.x;
    if (e < N_EDGES) atomicAdd(&bcnt[(dst[e] >> 7) * CPAD], 1);
}

// ---- scan bucket counts -> bbase (exclusive), init bcursor ----------------
__global__ __launch_bounds__(1024) void kBScan(const int* __restrict__ bcnt,
                                               int* __restrict__ bbase,
                                               int* __restrict__ bcursor,
                                               int* __restrict__ off) {
    __shared__ int sm[1024];
    int t = threadIdx.x;
    int v = (t < NBUCK) ? bcnt[t * CPAD] : 0;
    sm[t] = v;
    __syncthreads();
    for (int s = 1; s < 1024; s <<= 1) {
        int add = (t >= s) ? sm[t - s] : 0;
        __syncthreads();
        sm[t] += add;
        __syncthreads();
    }
    if (t < NBUCK) {
        int excl = sm[t] - v;
        bbase[t] = excl;
        bcursor[t * CPAD] = excl;
    }
    if (t == NBUCK - 1) bbase[NBUCK] = sm[t];
    if (t == 0) off[N_NODES] = N_EDGES;
}

// ---- bin edges: pairs[append(bucket)] = (src<<7)|(dst&127) ----------------
__global__ __launch_bounds__(256) void kBin(const int* __restrict__ src,
                                            const int* __restrict__ dst,
                                            int* __restrict__ bcursor,
                                            int* __restrict__ pairs) {
    int e = blockIdx.x * 256 + threadIdx.x;
    if (e < N_EDGES) {
        int d = dst[e];
        int pos = atomicAdd(&bcursor[(d >> 7) * CPAD], 1);
        pairs[pos] = (src[e] << 7) | (d & 127);
    }
}

// ---- per-bucket: LDS histogram -> off/dinv, scatter csr (contiguous) ------
__global__ __launch_bounds__(256) void kBuild(const int* __restrict__ pairs,
                                              const int* __restrict__ bbase,
                                              int* __restrict__ off,
                                              float* __restrict__ dinv,
                                              int* __restrict__ csr) {
    __shared__ int hist[128];
    __shared__ int sc[128];
    __shared__ int lcur[128];
    int b = blockIdx.x;
    int t = threadIdx.x;
    int ebeg = bbase[b], eend = bbase[b + 1];
    if (t < 128) hist[t] = 0;
    __syncthreads();
    for (int e = ebeg + t; e < eend; e += 256)
        atomicAdd(&hist[pairs[e] & 127], 1);
    __syncthreads();
    if (t < 128) sc[t] = hist[t];
    __syncthreads();
    for (int s = 1; s < 128; s <<= 1) {
        int add = (t >= s && t < 128) ? sc[t - s] : 0;
        __syncthreads();
        if (t < 128) sc[t] += add;
        __syncthreads();
    }
    if (t < 128) {
        int g = b * 128 + t;
        int excl = ebeg + sc[t] - hist[t];
        lcur[t] = excl;
        if (g < N_NODES) {
            off[g] = excl;
            dinv[g] = rsqrtf((float)hist[t] + 1.0f);  // +1 = self loop
        }
    }
    __syncthreads();
    for (int e = ebeg + t; e < eend; e += 256) {
        int v = pairs[e];
        int pos = atomicAdd(&lcur[v & 127], 1);
        csr[pos] = v >> 7;
    }
}

// ---------------- hp = (x @ W1) * dinv[n]  ---------------------------------
__global__ __launch_bounds__(256) void kGemm1(const float* __restrict__ x,
                                              const float* __restrict__ W1,
                                              const float* __restrict__ dinv,
                                              float* __restrict__ hp) {
    __shared__ float Ws[N_FEAT * HIDDEN];  // 8 KB
    for (int t = threadIdx.x; t < N_FEAT * HIDDEN; t += 256) Ws[t] = W1[t];
    __syncthreads();
    int n = blockIdx.x * 256 + threadIdx.x;
    if (n >= N_NODES) return;

    float acc[HIDDEN];
#pragma unroll
    for (int j = 0; j < HIDDEN; ++j) acc[j] = 0.f;

    const float4* xr = (const float4*)(x + (size_t)n * N_FEAT);
#pragma unroll 4
    for (int k4 = 0; k4 < N_FEAT / 4; ++k4) {
        float4 v = xr[k4];
        float xk[4] = {v.x, v.y, v.z, v.w};
#pragma unroll
        for (int kk = 0; kk < 4; ++kk) {
            const float4* wrow = (const float4*)&Ws[(k4 * 4 + kk) * HIDDEN];
#pragma unroll
            for (int j4 = 0; j4 < 4; ++j4) {
                float4 wv = wrow[j4];
                acc[j4 * 4 + 0] += xk[kk] * wv.x;
                acc[j4 * 4 + 1] += xk[kk] * wv.y;
                acc[j4 * 4 + 2] += xk[kk] * wv.z;
                acc[j4 * 4 + 3] += xk[kk] * wv.w;
            }
        }
    }
    float dv = dinv[n];
    float4* hr = (float4*)(hp + (size_t)n * HIDDEN);
#pragma unroll
    for (int j4 = 0; j4 < 4; ++j4)
        hr[j4] = make_float4(acc[j4 * 4 + 0] * dv, acc[j4 * 4 + 1] * dv,
                             acc[j4 * 4 + 2] * dv, acc[j4 * 4 + 3] * dv);
}

// ------- agg[n] = dinv[n] * (hp[n] + sum_{s in N(n)} hp[s]) ----------------
__global__ __launch_bounds__(256) void kAgg(const float* __restrict__ hp,
                                            const float* __restrict__ dinv,
                                            const int* __restrict__ off,
                                            const int* __restrict__ csr,
                                            float* __restrict__ agg) {
    int gid = blockIdx.x * 256 + threadIdx.x;
    int n = gid >> 4;
    int j = gid & 15;
    if (n >= N_NODES) return;
    int beg = off[n], end = off[n + 1];
    float acc = hp[(size_t)n * HIDDEN + j];  // self loop
    for (int eb = beg; eb < end; eb += 16) {
        int mye = eb + j;
        int sid = (mye < end) ? csr[mye] : -1;
#pragma unroll
        for (int k = 0; k < 16; ++k) {
            int s = __shfl(sid, k, 16);
            if (s >= 0) acc += hp[(size_t)s * HIDDEN + j];
        }
    }
    agg[(size_t)n * HIDDEN + j] = acc * dinv[n];
}

// ------- t = relu(agg1+b1); hp2 = (t @ W2) * dinv --------------------------
__global__ __launch_bounds__(256) void kLayer2(const float* __restrict__ agg1,
                                               const float* __restrict__ W2,
                                               const float* __restrict__ b1,
                                               const float* __restrict__ dinv,
                                               float* __restrict__ hp2) {
    __shared__ float Ws[HIDDEN * HIDDEN];
    __shared__ float bs[HIDDEN];
    if (threadIdx.x < HIDDEN * HIDDEN) Ws[threadIdx.x] = W2[threadIdx.x];
    if (threadIdx.x < HIDDEN) bs[threadIdx.x] = b1[threadIdx.x];
    __syncthreads();
    int n = blockIdx.x * 256 + threadIdx.x;
    if (n >= N_NODES) return;

    float t[HIDDEN];
    const float4* a1r = (const float4*)(agg1 + (size_t)n * HIDDEN);
#pragma unroll
    for (int j4 = 0; j4 < 4; ++j4) {
        float4 av = a1r[j4];
        t[j4 * 4 + 0] = fmaxf(av.x + bs[j4 * 4 + 0], 0.f);
        t[j4 * 4 + 1] = fmaxf(av.y + bs[j4 * 4 + 1], 0.f);
        t[j4 * 4 + 2] = fmaxf(av.z + bs[j4 * 4 + 2], 0.f);
        t[j4 * 4 + 3] = fmaxf(av.w + bs[j4 * 4 + 3], 0.f);
    }
    float acc[HIDDEN];
#pragma unroll
    for (int j = 0; j < HIDDEN; ++j) acc[j] = 0.f;
#pragma unroll
    for (int k = 0; k < HIDDEN; ++k) {
        const float4* wrow = (const float4*)&Ws[k * HIDDEN];
#pragma unroll
        for (int j4 = 0; j4 < 4; ++j4) {
            float4 wv = wrow[j4];
            acc[j4 * 4 + 0] += t[k] * wv.x;
            acc[j4 * 4 + 1] += t[k] * wv.y;
            acc[j4 * 4 + 2] += t[k] * wv.z;
            acc[j4 * 4 + 3] += t[k] * wv.w;
        }
    }
    float dv = dinv[n];
    float4* hr = (float4*)(hp2 + (size_t)n * HIDDEN);
#pragma unroll
    for (int j4 = 0; j4 < 4; ++j4)
        hr[j4] = make_float4(acc[j4 * 4 + 0] * dv, acc[j4 * 4 + 1] * dv,
                             acc[j4 * 4 + 2] * dv, acc[j4 * 4 + 3] * dv);
}

// ------- v = relu(agg2+b2); pooled[batch[n]] += v --------------------------
__global__ __launch_bounds__(256) void kPool(const float* __restrict__ agg2,
                                             const float* __restrict__ b2,
                                             const int* __restrict__ batch,
                                             float* __restrict__ pooled) {
    int gid = blockIdx.x * 256 + threadIdx.x;
    int n = gid >> 4;
    int j = gid & 15;
    if (n >= N_NODES) return;
    float v = fmaxf(agg2[(size_t)n * HIDDEN + j] + b2[j], 0.f);
    unsafeAtomicAdd(&pooled[(size_t)batch[n] * HIDDEN + j], v);
}

// ------- g=relu(pooled); g1=relu(g@lw1+lb1); out=g1@lw2+lb2 ----------------
__global__ __launch_bounds__(64) void kMlp(const float* __restrict__ pooled,
                                           const float* __restrict__ lw1,
                                           const float* __restrict__ lb1,
                                           const float* __restrict__ lw2,
                                           const float* __restrict__ lb2,
                                           float* __restrict__ out) {
    int g = blockIdx.x * 64 + threadIdx.x;
    if (g >= N_GRAPHS) return;
    float gv[HIDDEN];
#pragma unroll
    for (int k = 0; k < HIDDEN; ++k)
        gv[k] = fmaxf(pooled[(size_t)g * HIDDEN + k], 0.f);
    float o[N_CLASSES];
#pragma unroll
    for (int c = 0; c < N_CLASSES; ++c) o[c] = lb2[c];
    for (int j = 0; j < MLP_H; ++j) {
        float s = lb1[j];
#pragma unroll
        for (int k = 0; k < HIDDEN; ++k) s += gv[k] * lw1[k * MLP_H + j];
        s = fmaxf(s, 0.f);
#pragma unroll
        for (int c = 0; c < N_CLASSES; ++c) o[c] += s * lw2[j * N_CLASSES + c];
    }
#pragma unroll
    for (int c = 0; c < N_CLASSES; ++c) out[(size_t)g * N_CLASSES + c] = o[c];
}

extern "C" void kernel_launch(void* const* d_in, const int* in_sizes, int n_in,
                              void* d_out, int out_size, void* d_ws,
                              size_t ws_size, hipStream_t stream) {
    const float* x     = (const float*)d_in[0];
    const int*   ei    = (const int*)d_in[1];
    const int*   batch = (const int*)d_in[2];
    const float* W1    = (const float*)d_in[3];
    const float* b1    = (const float*)d_in[4];
    const float* W2    = (const float*)d_in[5];
    const float* b2    = (const float*)d_in[6];
    const float* lw1   = (const float*)d_in[7];
    const float* lb1   = (const float*)d_in[8];
    const float* lw2   = (const float*)d_in[9];
    const float* lb2   = (const float*)d_in[10];
    float* out = (float*)d_out;

    const int* src = ei;
    const int* dst = ei + N_EDGES;

    // workspace layout (bytes)
    char* ws = (char*)d_ws;
    int*   bcnt    = (int*)(ws + 0);         // 782*64 = 50048 -> 50176
    int*   bcursor = (int*)(ws + 50176);     // 50176
    int*   bbase   = (int*)(ws + 100352);    // 783*4 -> 4096
    float* dinv    = (float*)(ws + 104448);  // 400000 -> 401408
    int*   off     = (int*)(ws + 505856);    // 400004 -> 401408
    int*   pairs   = (int*)(ws + 907264);    // 12800000 (dead after kBuild)
    float* hp      = (float*)(ws + 907264);  //  6400000 (overlays pairs)
    float* agg     = (float*)(ws + 7307264); //  6400000 (overlays pairs)
    int*   csr     = (int*)(ws + 13707264);  // 12800000
    float* pooled  = (float*)(ws + 26507264);//    32768

    hipMemsetAsync(bcnt, 0, 50176, stream);
    hipMemsetAsync(pooled, 0, 32768, stream);

    kBCnt<<<(N_EDGES + 255) / 256, 256, 0, stream>>>(dst, bcnt);
    kBScan<<<1, 1024, 0, stream>>>(bcnt, bbase, bcursor, off);
    kBin<<<(N_EDGES + 255) / 256, 256, 0, stream>>>(src, dst, bcursor, pairs);
    kBuild<<<NBUCK, 256, 0, stream>>>(pairs, bbase, off, dinv, csr);

    kGemm1<<<NBLK, 256, 0, stream>>>(x, W1, dinv, hp);
    kAgg<<<(N_NODES * HIDDEN + 255) / 256, 256, 0, stream>>>(hp, dinv, off, csr, agg);
    kLayer2<<<NBLK, 256, 0, stream>>>(agg, W2, b1, dinv, hp);
    kAgg<<<(N_NODES * HIDDEN + 255) / 256, 256, 0, stream>>>(hp, dinv, off, csr, agg);
    kPool<<<(N_NODES * HIDDEN + 255) / 256, 256, 0, stream>>>(agg, b2, batch, pooled);
    kMlp<<<(N_GRAPHS + 63) / 64, 64, 0, stream>>>(pooled, lw1, lb1, lw2, lb2, out);
}

// Round 4
// 313.144 us; speedup vs baseline: 2.0683x; 1.9410x over previous
//
#include <hip/hip_runtime.h>

#define N_NODES   100000
#define N_EDGES   3200000
#define N_FEAT    128
#define HIDDEN    16
#define MLP_H     100
#define N_CLASSES 12
#define N_GRAPHS  512
#define NBLK      391            // ceil(N_NODES/256)
#define BNODES    512            // nodes per bucket (dst>>9)
#define NBUCK     196            // ceil(N_NODES/512)
#define CPAD      16             // counter padding (ints) -> 1 counter / 64B
#define RING      64             // LDS ring slots per bucket in kBin

// ---- bucket histogram (LDS-staged): bcnt[d>>9] += ... ---------------------
__global__ __launch_bounds__(256) void kBCnt(const int* __restrict__ dst,
                                             int* __restrict__ bcnt) {
    __shared__ int h[NBUCK];
    int t = threadIdx.x;
    for (int i = t; i < NBUCK; i += 256) h[i] = 0;
    __syncthreads();
    int nquad = N_EDGES / 4;
    for (int i = blockIdx.x * 256 + t; i < nquad; i += gridDim.x * 256) {
        int4 d4 = ((const int4*)dst)[i];
        atomicAdd(&h[d4.x >> 9], 1);
        atomicAdd(&h[d4.y >> 9], 1);
        atomicAdd(&h[d4.z >> 9], 1);
        atomicAdd(&h[d4.w >> 9], 1);
    }
    __syncthreads();
    for (int i = t; i < NBUCK; i += 256)
        if (h[i]) atomicAdd(&bcnt[i * CPAD], h[i]);
}

// ---- scan: true bases tb[], 16-aligned padded bases pb[] -> gcursor -------
__global__ __launch_bounds__(256) void kBScan(const int* __restrict__ bcnt,
                                              int* __restrict__ tb,
                                              int* __restrict__ pb,
                                              int* __restrict__ gcursor,
                                              int* __restrict__ off) {
    __shared__ int s1[256], s2[256];
    int t = threadIdx.x;
    int c  = (t < NBUCK) ? bcnt[t * CPAD] : 0;
    int ca = (c + 15) & ~15;
    s1[t] = c; s2[t] = ca;
    __syncthreads();
    for (int s = 1; s < 256; s <<= 1) {
        int a1 = (t >= s) ? s1[t - s] : 0;
        int a2 = (t >= s) ? s2[t - s] : 0;
        __syncthreads();
        s1[t] += a1; s2[t] += a2;
        __syncthreads();
    }
    if (t < NBUCK) {
        tb[t] = s1[t] - c;
        int p = s2[t] - ca;
        pb[t] = p;
        gcursor[t * CPAD] = p;
    }
    if (t == 0) { tb[NBUCK] = N_EDGES; off[N_NODES] = N_EDGES; }
}

// ---- LDS-staged binning: 64B single-writer chunk flushes ------------------
__global__ __launch_bounds__(512) void kBin(const int* __restrict__ src,
                                            const int* __restrict__ dst,
                                            int* __restrict__ gcursor,
                                            int* __restrict__ pairs) {
    __shared__ int ring[NBUCK * RING];   // 50176 B
    __shared__ int cnt[NBUCK];
    __shared__ int fl[NBUCK];
    int t = threadIdx.x;
    for (int i = t; i < NBUCK; i += 512) { cnt[i] = 0; fl[i] = 0; }
    __syncthreads();
    const int batch = 512 * 4;                       // 2048 edges per block-iter
    for (int base = blockIdx.x * batch; base < N_EDGES;
         base += gridDim.x * batch) {
        int e0 = base + t * 4;
        if (e0 < N_EDGES) {                          // N_EDGES % 4 == 0
            int4 d4 = *(const int4*)&dst[e0];
            int4 s4 = *(const int4*)&src[e0];
            int dd[4] = {d4.x, d4.y, d4.z, d4.w};
            int ss[4] = {s4.x, s4.y, s4.z, s4.w};
#pragma unroll
            for (int k = 0; k < 4; ++k) {
                int b = dd[k] >> 9;
                int p = atomicAdd(&cnt[b], 1);
                ring[b * RING + (p & (RING - 1))] = (ss[k] << 9) | (dd[k] & 511);
            }
        }
        __syncthreads();
        if (t < NBUCK) {
            while (cnt[t] - fl[t] >= 16) {
                int start = fl[t];
                int gpos = atomicAdd(&gcursor[t * CPAD], 16);
                int rbase = t * RING + (start & (RING - 1)); // 16-aligned, no wrap
                if ((gpos & 3) == 0) {
                    const int4* rp = (const int4*)&ring[rbase];
                    int4* gp = (int4*)&pairs[gpos];
                    gp[0] = rp[0]; gp[1] = rp[1]; gp[2] = rp[2]; gp[3] = rp[3];
                } else {
#pragma unroll
                    for (int k = 0; k < 16; ++k) pairs[gpos + k] = ring[rbase + k];
                }
                fl[t] = start + 16;
            }
        }
        __syncthreads();
    }
    if (t < NBUCK) {
        int pending = cnt[t] - fl[t];
        if (pending > 0) {
            int gpos = atomicAdd(&gcursor[t * CPAD], pending);
            for (int k = 0; k < pending; ++k)
                pairs[gpos + k] = ring[t * RING + ((fl[t] + k) & (RING - 1))];
        }
    }
}

// ---- per-bucket: LDS hist -> off/dinv, scatter csr (contiguous window) ----
__global__ __launch_bounds__(512) void kBuild(const int* __restrict__ pairs,
                                              const int* __restrict__ tb,
                                              const int* __restrict__ pb,
                                              int* __restrict__ off,
                                              float* __restrict__ dinv,
                                              int* __restrict__ csr) {
    __shared__ int hist[BNODES];
    __shared__ int sc[BNODES];
    __shared__ int lcur[BNODES];
    int b = blockIdx.x, t = threadIdx.x;
    int ebeg = tb[b];
    int ecnt = tb[b + 1] - ebeg;
    int pbeg = pb[b];
    hist[t] = 0;
    __syncthreads();
    for (int i = t; i < ecnt; i += 512)
        atomicAdd(&hist[pairs[pbeg + i] & 511], 1);
    __syncthreads();
    sc[t] = hist[t];
    __syncthreads();
    for (int s = 1; s < 512; s <<= 1) {
        int a = (t >= s) ? sc[t - s] : 0;
        __syncthreads();
        sc[t] += a;
        __syncthreads();
    }
    int g = b * BNODES + t;
    int excl = ebeg + sc[t] - hist[t];
    lcur[t] = excl;
    if (g < N_NODES) {
        off[g] = excl;
        dinv[g] = rsqrtf((float)hist[t] + 1.0f);  // +1 = self loop
    }
    __syncthreads();
    for (int i = t; i < ecnt; i += 512) {
        int v = pairs[pbeg + i];
        int pos = atomicAdd(&lcur[v & 511], 1);
        csr[pos] = v >> 9;
    }
}

// ---------------- hp = (x @ W1) * dinv[n]  ---------------------------------
__global__ __launch_bounds__(256) void kGemm1(const float* __restrict__ x,
                                              const float* __restrict__ W1,
                                              const float* __restrict__ dinv,
                                              float* __restrict__ hp) {
    __shared__ float Ws[N_FEAT * HIDDEN];  // 8 KB
    for (int t = threadIdx.x; t < N_FEAT * HIDDEN; t += 256) Ws[t] = W1[t];
    __syncthreads();
    int n = blockIdx.x * 256 + threadIdx.x;
    if (n >= N_NODES) return;

    float acc[HIDDEN];
#pragma unroll
    for (int j = 0; j < HIDDEN; ++j) acc[j] = 0.f;

    const float4* xr = (const float4*)(x + (size_t)n * N_FEAT);
#pragma unroll 4
    for (int k4 = 0; k4 < N_FEAT / 4; ++k4) {
        float4 v = xr[k4];
        float xk[4] = {v.x, v.y, v.z, v.w};
#pragma unroll
        for (int kk = 0; kk < 4; ++kk) {
            const float4* wrow = (const float4*)&Ws[(k4 * 4 + kk) * HIDDEN];
#pragma unroll
            for (int j4 = 0; j4 < 4; ++j4) {
                float4 wv = wrow[j4];
                acc[j4 * 4 + 0] += xk[kk] * wv.x;
                acc[j4 * 4 + 1] += xk[kk] * wv.y;
                acc[j4 * 4 + 2] += xk[kk] * wv.z;
                acc[j4 * 4 + 3] += xk[kk] * wv.w;
            }
        }
    }
    float dv = dinv[n];
    float4* hr = (float4*)(hp + (size_t)n * HIDDEN);
#pragma unroll
    for (int j4 = 0; j4 < 4; ++j4)
        hr[j4] = make_float4(acc[j4 * 4 + 0] * dv, acc[j4 * 4 + 1] * dv,
                             acc[j4 * 4 + 2] * dv, acc[j4 * 4 + 3] * dv);
}

// ------- agg[n] = dinv[n] * (hp[n] + sum_{s in N(n)} hp[s]) ----------------
__global__ __launch_bounds__(256) void kAgg(const float* __restrict__ hp,
                                            const float* __restrict__ dinv,
                                            const int* __restrict__ off,
                                            const int* __restrict__ csr,
                                            float* __restrict__ agg) {
    int gid = blockIdx.x * 256 + threadIdx.x;
    int n = gid >> 4;
    int j = gid & 15;
    if (n >= N_NODES) return;
    int beg = off[n], end = off[n + 1];
    float acc = hp[(size_t)n * HIDDEN + j];  // self loop
    for (int eb = beg; eb < end; eb += 16) {
        int mye = eb + j;
        int sid = (mye < end) ? csr[mye] : -1;
#pragma unroll
        for (int k = 0; k < 16; ++k) {
            int s = __shfl(sid, k, 16);
            if (s >= 0) acc += hp[(size_t)s * HIDDEN + j];
        }
    }
    agg[(size_t)n * HIDDEN + j] = acc * dinv[n];
}

// ------- t = relu(agg1+b1); hp2 = (t @ W2) * dinv --------------------------
__global__ __launch_bounds__(256) void kLayer2(const float* __restrict__ agg1,
                                               const float* __restrict__ W2,
                                               const float* __restrict__ b1,
                                               const float* __restrict__ dinv,
                                               float* __restrict__ hp2) {
    __shared__ float Ws[HIDDEN * HIDDEN];
    __shared__ float bs[HIDDEN];
    if (threadIdx.x < HIDDEN * HIDDEN) Ws[threadIdx.x] = W2[threadIdx.x];
    if (threadIdx.x < HIDDEN) bs[threadIdx.x] = b1[threadIdx.x];
    __syncthreads();
    int n = blockIdx.x * 256 + threadIdx.x;
    if (n >= N_NODES) return;

    float t[HIDDEN];
    const float4* a1r = (const float4*)(agg1 + (size_t)n * HIDDEN);
#pragma unroll
    for (int j4 = 0; j4 < 4; ++j4) {
        float4 av = a1r[j4];
        t[j4 * 4 + 0] = fmaxf(av.x + bs[j4 * 4 + 0], 0.f);
        t[j4 * 4 + 1] = fmaxf(av.y + bs[j4 * 4 + 1], 0.f);
        t[j4 * 4 + 2] = fmaxf(av.z + bs[j4 * 4 + 2], 0.f);
        t[j4 * 4 + 3] = fmaxf(av.w + bs[j4 * 4 + 3], 0.f);
    }
    float acc[HIDDEN];
#pragma unroll
    for (int j = 0; j < HIDDEN; ++j) acc[j] = 0.f;
#pragma unroll
    for (int k = 0; k < HIDDEN; ++k) {
        const float4* wrow = (const float4*)&Ws[k * HIDDEN];
#pragma unroll
        for (int j4 = 0; j4 < 4; ++j4) {
            float4 wv = wrow[j4];
            acc[j4 * 4 + 0] += t[k] * wv.x;
            acc[j4 * 4 + 1] += t[k] * wv.y;
            acc[j4 * 4 + 2] += t[k] * wv.z;
            acc[j4 * 4 + 3] += t[k] * wv.w;
        }
    }
    float dv = dinv[n];
    float4* hr = (float4*)(hp2 + (size_t)n * HIDDEN);
#pragma unroll
    for (int j4 = 0; j4 < 4; ++j4)
        hr[j4] = make_float4(acc[j4 * 4 + 0] * dv, acc[j4 * 4 + 1] * dv,
                             acc[j4 * 4 + 2] * dv, acc[j4 * 4 + 3] * dv);
}

// ------- v = relu(agg2+b2); pooled[batch[n]] += v --------------------------
__global__ __launch_bounds__(256) void kPool(const float* __restrict__ agg2,
                                             const float* __restrict__ b2,
                                             const int* __restrict__ batch,
                                             float* __restrict__ pooled) {
    int gid = blockIdx.x * 256 + threadIdx.x;
    int n = gid >> 4;
    int j = gid & 15;
    if (n >= N_NODES) return;
    float v = fmaxf(agg2[(size_t)n * HIDDEN + j] + b2[j], 0.f);
    unsafeAtomicAdd(&pooled[(size_t)batch[n] * HIDDEN + j], v);
}

// ------- g=relu(pooled); g1=relu(g@lw1+lb1); out=g1@lw2+lb2 ----------------
__global__ __launch_bounds__(64) void kMlp(const float* __restrict__ pooled,
                                           const float* __restrict__ lw1,
                                           const float* __restrict__ lb1,
                                           const float* __restrict__ lw2,
                                           const float* __restrict__ lb2,
                                           float* __restrict__ out) {
    int g = blockIdx.x * 64 + threadIdx.x;
    if (g >= N_GRAPHS) return;
    float gv[HIDDEN];
#pragma unroll
    for (int k = 0; k < HIDDEN; ++k)
        gv[k] = fmaxf(pooled[(size_t)g * HIDDEN + k], 0.f);
    float o[N_CLASSES];
#pragma unroll
    for (int c = 0; c < N_CLASSES; ++c) o[c] = lb2[c];
    for (int j = 0; j < MLP_H; ++j) {
        float s = lb1[j];
#pragma unroll
        for (int k = 0; k < HIDDEN; ++k) s += gv[k] * lw1[k * MLP_H + j];
        s = fmaxf(s, 0.f);
#pragma unroll
        for (int c = 0; c < N_CLASSES; ++c) o[c] += s * lw2[j * N_CLASSES + c];
    }
#pragma unroll
    for (int c = 0; c < N_CLASSES; ++c) out[(size_t)g * N_CLASSES + c] = o[c];
}

extern "C" void kernel_launch(void* const* d_in, const int* in_sizes, int n_in,
                              void* d_out, int out_size, void* d_ws,
                              size_t ws_size, hipStream_t stream) {
    const float* x     = (const float*)d_in[0];
    const int*   ei    = (const int*)d_in[1];
    const int*   batch = (const int*)d_in[2];
    const float* W1    = (const float*)d_in[3];
    const float* b1    = (const float*)d_in[4];
    const float* W2    = (const float*)d_in[5];
    const float* b2    = (const float*)d_in[6];
    const float* lw1   = (const float*)d_in[7];
    const float* lb1   = (const float*)d_in[8];
    const float* lw2   = (const float*)d_in[9];
    const float* lb2   = (const float*)d_in[10];
    float* out = (float*)d_out;

    const int* src = ei;
    const int* dst = ei + N_EDGES;

    // workspace layout (bytes, 512-aligned offsets)
    char* ws = (char*)d_ws;
    int*   bcnt    = (int*)(ws + 0);         // 196*64 = 12544
    int*   gcursor = (int*)(ws + 16384);     // 12544
    int*   tb      = (int*)(ws + 32768);     // 788
    int*   pb      = (int*)(ws + 36864);     // 788
    float* dinv    = (float*)(ws + 40960);   // 400000
    int*   off     = (int*)(ws + 442368);    // 400004
    int*   pairs   = (int*)(ws + 843776);    // 12812544 (padded; dead after kBuild)
    float* hp      = (float*)(ws + 843776);  //  6400000 (overlays pairs)
    float* agg     = (float*)(ws + 7243776); //  6400000 (overlays pairs)
    int*   csr     = (int*)(ws + 13656576);  // 12800000
    float* pooled  = (float*)(ws + 26456576);//    32768

    hipMemsetAsync(bcnt, 0, NBUCK * CPAD * 4, stream);
    hipMemsetAsync(pooled, 0, 32768, stream);

    kBCnt<<<256, 256, 0, stream>>>(dst, bcnt);
    kBScan<<<1, 256, 0, stream>>>(bcnt, tb, pb, gcursor, off);
    kBin<<<128, 512, 0, stream>>>(src, dst, gcursor, pairs);
    kBuild<<<NBUCK, 512, 0, stream>>>(pairs, tb, pb, off, dinv, csr);

    kGemm1<<<NBLK, 256, 0, stream>>>(x, W1, dinv, hp);
    kAgg<<<(N_NODES * HIDDEN + 255) / 256, 256, 0, stream>>>(hp, dinv, off, csr, agg);
    kLayer2<<<NBLK, 256, 0, stream>>>(agg, W2, b1, dinv, hp);
    kAgg<<<(N_NODES * HIDDEN + 255) / 256, 256, 0, stream>>>(hp, dinv, off, csr, agg);
    kPool<<<(N_NODES * HIDDEN + 255) / 256, 256, 0, stream>>>(agg, b2, batch, pooled);
    kMlp<<<(N_GRAPHS + 63) / 64, 64, 0, stream>>>(pooled, lw1, lb1, lw2, lb2, out);
}